// Round 10
// baseline (314.483 us; speedup 1.0000x reference)
//
#include <hip/hip_runtime.h>

#define BN_EPS 1e-3f

typedef __attribute__((ext_vector_type(8))) short bf16x8;
typedef __attribute__((ext_vector_type(4))) short short4v;
typedef __attribute__((ext_vector_type(4))) float f32x4;

__device__ __forceinline__ short f2bf(float f) {
    union { float f; unsigned u; } a; a.f = f;
    unsigned r = a.u + 0x7fffu + ((a.u >> 16) & 1u);
    return (short)(r >> 16);
}
__device__ __forceinline__ float bf2f(short s) {
    union { unsigned u; float f; } a;
    a.u = ((unsigned)(unsigned short)s) << 16;
    return a.f;
}

// ---------------- K-1: compress binary a -> bitmask -------------------------
// word t covers row = t>>5, k = (t&31)*32 + bit. bit j of quad q = k_local q*4+j.
__global__ __launch_bounds__(256) void prep_a(const float* __restrict__ a,
                                              uint* __restrict__ abits) {
    const size_t t = (size_t)blockIdx.x * 256 + threadIdx.x;   // 1,048,576 words
    const float* src = a + t * 32;
    uint w = 0;
    #pragma unroll
    for (int q = 0; q < 8; ++q) {
        f32x4 v = *reinterpret_cast<const f32x4*>(src + q * 4);
        w |= (v.x != 0.f ? 1u : 0u) << (q * 4);
        w |= (v.y != 0.f ? 2u : 0u) << (q * 4);
        w |= (v.z != 0.f ? 4u : 0u) << (q * 4);
        w |= (v.w != 0.f ? 8u : 0u) << (q * 4);
    }
    abits[t] = w;
}

// ---------------- K0: pre-split x into hi/lo LDS chunk images ---------------
__global__ __launch_bounds__(512) void prep_x(const float* __restrict__ x,
                                              ushort* __restrict__ Xp) {
    const int b  = blockIdx.x >> 5;
    const int kc = blockIdx.x & 31;
    const int t  = threadIdx.x;
    const int f  = t & 127;
    const int kg = t >> 7;             // 0..3
    bf16x8 hi8, lo8;
    #pragma unroll
    for (int e = 0; e < 8; ++e) {
        const float val = x[((size_t)b * 1024 + kc * 32 + kg * 8 + e) * 128 + f];
        const short h = f2bf(val);
        hi8[e] = h; lo8[e] = f2bf(val - bf2f(h));
    }
    const size_t base = ((size_t)(b * 32 + kc)) * 8192 + (size_t)kg * 1024 + (size_t)f * 8;
    *reinterpret_cast<bf16x8*>(&Xp[base])        = hi8;
    *reinterpret_cast<bf16x8*>(&Xp[base + 4096]) = lo8;
}

// ---------------- K2: W pre-split + pool zero (fold) ------------------------
__global__ __launch_bounds__(256) void prep_w(
    const float* __restrict__ w1, const float* __restrict__ w2,
    const float* __restrict__ w3, ushort* __restrict__ Wp,
    float* __restrict__ pool) {
    const int k = blockIdx.x;      // 0..639 global k row
    const int c = threadIdx.x;     // 0..255
    if (k < 32) pool[k * 256 + c] = 0.0f;      // relu floor init
    const float* src; int kl, base;
    if (k < 128)      { src = w1; kl = k;       base = 0; }
    else if (k < 384) { src = w2; kl = k - 128; base = 65536; }
    else              { src = w3; kl = k - 384; base = 196608; }
    const float val = src[(size_t)kl * 256 + c];
    const short hi = f2bf(val);
    const short lo = f2bf(val - bf2f(hi));
    const int off = base + (kl >> 5) * 16384 + ((((kl >> 3) & 3) * 256 + c) * 8) + (kl & 7);
    Wp[off]        = (ushort)hi;
    Wp[off + 8192] = (ushort)lo;
}

// ---------------- MEGA: agg (bitmask A) + 3-layer MLP + max-pool ------------
// 512 blocks x 512 thr (8 waves). XCD-aware: batch pinned to one XCD.
// Phase A: A-operand expanded from bitmask in regs (no LDS staging, no HBM a).
// Phase B: verified pipelined 3-layer MLP. All frag layouts HW-verified.
__global__ __launch_bounds__(512, 4) void mega_gin(
    const float* __restrict__ x, const uint* __restrict__ abits,
    const ushort* __restrict__ Xp, const ushort* __restrict__ Wp,
    const float* __restrict__ epsp,
    const float* __restrict__ b1, const float* __restrict__ g1,
    const float* __restrict__ be1, const float* __restrict__ m1,
    const float* __restrict__ v1,
    const float* __restrict__ b2, const float* __restrict__ g2,
    const float* __restrict__ be2, const float* __restrict__ m2,
    const float* __restrict__ v2,
    const float* __restrict__ b3, const float* __restrict__ g3,
    const float* __restrict__ be3, const float* __restrict__ m3,
    const float* __restrict__ v3,
    float* __restrict__ pool) {

    // 80 KB LDS union (barrier-separated aliasing, layout preserved from r8)
    __shared__ __align__(16) char smem[81920];
    auto Xhl = reinterpret_cast<ushort(*)[2][2][4][128][8]>(smem + 16384);// [buf][half][pl][kg][f][e] 64 KB
    auto Red = reinterpret_cast<f32x4(*)[2][64][8]>(smem);                // [wr][fg][lane][frag]      16 KB
    auto Wb  = reinterpret_cast<ushort(*)[2][4][256][8]>(smem);           // [buf][pl][kg][c][e]       64 KB
    auto Ab  = reinterpret_cast<ushort(*)[2][2][4][32][8]>(smem + 65536); // [buf][pl][wr][kg][row][e] 16 KB

    const int tid  = threadIdx.x;
    const int lane = tid & 63;
    const int wid  = tid >> 6;
    const int wr   = wid >> 2;       // 0..1: 32-row group (both phases)
    const int wn   = wid & 3;        // phase B col-group (64 cols)
    const int fg   = wid & 1;        // phase A f-group (64 f)
    const int kh   = (wid >> 1) & 1; // phase A k-half (512 nodes)
    const int lr   = lane & 15;
    const int kg   = lane >> 4;

    // XCD-aware block mapping: all 16 tiles of a batch on one XCD
    const int xcd   = blockIdx.x & 7;
    const int idx   = blockIdx.x >> 3;
    const int batch = xcd * 4 + (idx & 3);
    const int tile  = idx >> 2;          // 0..15
    const int row0  = tile * 64;

    const ushort* xp = Xp + (size_t)batch * 32 * 8192;
    // bit word for (row, k): abits[row_g*32 + (k>>5)], bit k&31.
    // phase A wave needs k = kh*512 + s*32 + kg*8 + e  -> word kh*16+s, bits kg*8..+7
    const uint* bb0 = abits + ((size_t)batch * 1024 + row0 + wr * 32 + lr) * 32 + kh * 16;
    const uint* bb1 = bb0 + 16 * 32;     // +16 rows

    f32x4 aa[2][4] = {};             // agg accumulator

#define AGGX_LOAD(S, X0, X1, X2, X3)                                                      \
    {   const f32x4* x0_ = reinterpret_cast<const f32x4*>(xp + (size_t)(S) * 8192);       \
        const f32x4* x1_ = reinterpret_cast<const f32x4*>(xp + (size_t)(16 + (S)) * 8192);\
        X0 = x0_[tid]; X1 = x0_[512 + tid]; X2 = x1_[tid]; X3 = x1_[512 + tid]; }

#define AGGX_WRITE(BUF, X0, X1, X2, X3)                                                   \
    {   f32x4* xd_ = reinterpret_cast<f32x4*>(&Xhl[BUF][0][0][0][0][0]);                  \
        xd_[tid] = X0; xd_[512 + tid] = X1; xd_[1024 + tid] = X2; xd_[1536 + tid] = X3; }

#define EXPAND(W, AF)                                                                     \
    {   _Pragma("unroll")                                                                 \
        for (int e = 0; e < 8; ++e)                                                       \
            AF[e] = (short)((((W) >> (kg * 8 + e)) & 1u) ? 0x3F80 : 0); }

    // ---- Phase A: 16 stages, Xhl dbuf, bits+X prefetched 1 stage ahead ----
    f32x4 xv0, xv1, xv2, xv3;
    AGGX_LOAD(0, xv0, xv1, xv2, xv3);
    uint w0 = bb0[0], w1 = bb1[0];
    AGGX_WRITE(0, xv0, xv1, xv2, xv3);

    for (int s = 0; s < 16; ++s) {
        const int buf = s & 1;
        __syncthreads();
        f32x4 nx0, nx1, nx2, nx3;
        uint nw0, nw1;
        if (s + 1 < 16) {
            AGGX_LOAD(s + 1, nx0, nx1, nx2, nx3);
            nw0 = bb0[s + 1]; nw1 = bb1[s + 1];
        }
        bf16x8 af0, af1;
        EXPAND(w0, af0);
        EXPAND(w1, af1);
        #pragma unroll
        for (int ni = 0; ni < 4; ++ni) {
            const int c = fg * 64 + ni * 16 + lr;
            bf16x8 bh = *reinterpret_cast<bf16x8*>(&Xhl[buf][kh][0][kg][c][0]);
            bf16x8 bl = *reinterpret_cast<bf16x8*>(&Xhl[buf][kh][1][kg][c][0]);
            aa[0][ni] = __builtin_amdgcn_mfma_f32_16x16x32_bf16(af0, bh, aa[0][ni], 0, 0, 0);
            aa[0][ni] = __builtin_amdgcn_mfma_f32_16x16x32_bf16(af0, bl, aa[0][ni], 0, 0, 0);
            aa[1][ni] = __builtin_amdgcn_mfma_f32_16x16x32_bf16(af1, bh, aa[1][ni], 0, 0, 0);
            aa[1][ni] = __builtin_amdgcn_mfma_f32_16x16x32_bf16(af1, bl, aa[1][ni], 0, 0, 0);
        }
        w0 = nw0; w1 = nw1;
        if (s + 1 < 16) AGGX_WRITE(buf ^ 1, nx0, nx1, nx2, nx3);
    }

    // ---- Phase B macros (r7/r8 verified) ----
    f32x4 acc1[2][4] = {};
    f32x4 acc2[2][4] = {};

#define MLP_LOADW(BASE, KC, W0, W1, W2, W3)                                               \
    {   const f32x4* ws_ = reinterpret_cast<const f32x4*>(Wp + (BASE) + (KC) * 16384);    \
        W0 = ws_[tid]; W1 = ws_[512 + tid]; W2 = ws_[1024 + tid]; W3 = ws_[1536 + tid]; }

#define MLP_WRITEW(BUF, W0, W1, W2, W3)                                                   \
    {   f32x4* wd_ = reinterpret_cast<f32x4*>(&Wb[BUF][0][0][0][0]);                      \
        wd_[tid] = W0; wd_[512 + tid] = W1; wd_[1024 + tid] = W2; wd_[1536 + tid] = W3; }

#define MLP_REDIST(BUF, KC, SRC)                                                          \
    if (wn == ((KC) >> 1)) {                                                              \
        _Pragma("unroll")                                                                 \
        for (int j = 0; j < 2; ++j) {                                                     \
            const int ni  = ((KC) & 1) * 2 + j;                                           \
            const int kgw = j * 2 + (lr >> 3);                                            \
            const int e   = lr & 7;                                                       \
            _Pragma("unroll")                                                             \
            for (int mi = 0; mi < 2; ++mi)                                                \
                _Pragma("unroll")                                                         \
                for (int r = 0; r < 4; ++r) {                                             \
                    const float val_ = SRC[mi][ni][r];                                    \
                    const short h_ = f2bf(val_);                                          \
                    Ab[BUF][0][wr][kgw][mi * 16 + kg * 4 + r][e] = (ushort)h_;            \
                    Ab[BUF][1][wr][kgw][mi * 16 + kg * 4 + r][e] = (ushort)f2bf(val_ - bf2f(h_)); \
                }                                                                         \
        }                                                                                 \
    }

#define MLP_COMPUTE(BUF, DST)                                                             \
    {   bf16x8 ah0 = *reinterpret_cast<bf16x8*>(&Ab[BUF][0][wr][kg][lr][0]);              \
        bf16x8 al0 = *reinterpret_cast<bf16x8*>(&Ab[BUF][1][wr][kg][lr][0]);              \
        bf16x8 ah1 = *reinterpret_cast<bf16x8*>(&Ab[BUF][0][wr][kg][16 + lr][0]);         \
        bf16x8 al1 = *reinterpret_cast<bf16x8*>(&Ab[BUF][1][wr][kg][16 + lr][0]);         \
        _Pragma("unroll")                                                                 \
        for (int ni = 0; ni < 4; ++ni) {                                                  \
            bf16x8 bh = *reinterpret_cast<bf16x8*>(&Wb[BUF][0][kg][wn * 64 + ni * 16 + lr][0]); \
            bf16x8 bl = *reinterpret_cast<bf16x8*>(&Wb[BUF][1][kg][wn * 64 + ni * 16 + lr][0]); \
            DST[0][ni] = __builtin_amdgcn_mfma_f32_16x16x32_bf16(ah0, bh, DST[0][ni], 0, 0, 0); \
            DST[0][ni] = __builtin_amdgcn_mfma_f32_16x16x32_bf16(ah0, bl, DST[0][ni], 0, 0, 0); \
            DST[0][ni] = __builtin_amdgcn_mfma_f32_16x16x32_bf16(al0, bh, DST[0][ni], 0, 0, 0); \
            DST[1][ni] = __builtin_amdgcn_mfma_f32_16x16x32_bf16(ah1, bh, DST[1][ni], 0, 0, 0); \
            DST[1][ni] = __builtin_amdgcn_mfma_f32_16x16x32_bf16(ah1, bl, DST[1][ni], 0, 0, 0); \
            DST[1][ni] = __builtin_amdgcn_mfma_f32_16x16x32_bf16(al1, bh, DST[1][ni], 0, 0, 0); \
        }                                                                                 \
    }

#define MLP_BN(ACC, G, V, BE, M, BI)                                                      \
    _Pragma("unroll")                                                                     \
    for (int ni = 0; ni < 4; ++ni) {                                                      \
        const int c = wn * 64 + ni * 16 + lr;                                             \
        const float s_  = G[c] * rsqrtf(V[c] + BN_EPS);                                   \
        const float tt_ = BE[c] - M[c] * s_;                                              \
        const float bb_ = BI[c];                                                          \
        _Pragma("unroll")                                                                 \
        for (int mi = 0; mi < 2; ++mi)                                                    \
            _Pragma("unroll")                                                             \
            for (int r = 0; r < 4; ++r)                                                   \
                ACC[mi][ni][r] = fmaxf(fmaf(ACC[mi][ni][r] + bb_, s_, tt_), 0.f);         \
    }

    f32x4 wv0, wv1, wv2, wv3, wn0, wn1, wn2, wn3;

    // ---- Transition: reduce k-halves, x-epilogue, REDIST -> L1 chunk 0 ----
    MLP_LOADW(0, 0, wv0, wv1, wv2, wv3);     // issue early (reg-only)
    __syncthreads();                         // phase A reads of Xhl complete
    if (kh == 1) {
        #pragma unroll
        for (int mi = 0; mi < 2; ++mi)
            #pragma unroll
            for (int ni = 0; ni < 4; ++ni)
                Red[wr][fg][lane][mi * 4 + ni] = aa[mi][ni];
    }
    __syncthreads();
    if (kh == 0) {
        const float ep1 = 1.0f + epsp[0];
        const float* xb = x + (size_t)batch * 131072;
        #pragma unroll
        for (int ni = 0; ni < 4; ++ni) {
            const int col = fg * 64 + ni * 16 + lr;
            #pragma unroll
            for (int mi = 0; mi < 2; ++mi) {
                const int rbase = row0 + wr * 32 + mi * 16 + kg * 4;
                #pragma unroll
                for (int r = 0; r < 4; ++r) {
                    float t = aa[mi][ni][r] + Red[wr][fg][lane][mi * 4 + ni][r];
                    aa[mi][ni][r] = fmaf(ep1, xb[(size_t)(rbase + r) * 128 + col], t);
                }
            }
        }
        MLP_REDIST(0, 0, aa);               // Ab region = dead Xhl top
    }
    __syncthreads();                         // Red consumed; Ab[0] committed
    MLP_WRITEW(0, wv0, wv1, wv2, wv3);       // Wb[0] clobbers Red (post-barrier)

    // ---- Layer 1: 4 chunk-stages (A via REDIST from aa) ----
    #pragma unroll
    for (int s = 0; s < 4; ++s) {
        const int buf = s & 1;
        __syncthreads();
        if (s < 3) { MLP_LOADW(0, s + 1, wn0, wn1, wn2, wn3); }
        else       { MLP_LOADW(65536, 0, wn0, wn1, wn2, wn3); }
        MLP_COMPUTE(buf, acc1);
        MLP_WRITEW(buf ^ 1, wn0, wn1, wn2, wn3);
        if (s < 3) MLP_REDIST(buf ^ 1, s + 1, aa);
    }
    MLP_BN(acc1, g1, v1, be1, m1, b1);
    MLP_REDIST(0, 0, acc1);

    // ---- Layer 2: 8 chunk-stages ----
    #pragma unroll
    for (int s = 0; s < 8; ++s) {
        const int buf = s & 1;
        __syncthreads();
        if (s < 7) { MLP_LOADW(65536, s + 1, wn0, wn1, wn2, wn3); }
        else       { MLP_LOADW(196608, 0, wn0, wn1, wn2, wn3); }
        MLP_COMPUTE(buf, acc2);
        MLP_WRITEW(buf ^ 1, wn0, wn1, wn2, wn3);
        if (s < 7) MLP_REDIST(buf ^ 1, s + 1, acc1);
    }
    MLP_BN(acc2, g2, v2, be2, m2, b2);

    // ---- Layer 3 ----
    #pragma unroll
    for (int mi = 0; mi < 2; ++mi)
        #pragma unroll
        for (int ni = 0; ni < 4; ++ni)
            #pragma unroll
            for (int r = 0; r < 4; ++r)
                acc1[mi][ni][r] = 0.f;
    MLP_REDIST(0, 0, acc2);

    #pragma unroll
    for (int s = 0; s < 8; ++s) {
        const int buf = s & 1;
        __syncthreads();
        if (s < 7) { MLP_LOADW(196608, s + 1, wn0, wn1, wn2, wn3); }
        MLP_COMPUTE(buf, acc1);
        if (s < 7) {
            MLP_WRITEW(buf ^ 1, wn0, wn1, wn2, wn3);
            MLP_REDIST(buf ^ 1, s + 1, acc2);
        }
    }

    // epilogue 3: bias+BN+relu -> wave max -> atomicMax pool
    #pragma unroll
    for (int ni = 0; ni < 4; ++ni) {
        const int c = wn * 64 + ni * 16 + lr;
        const float s  = g3[c] * rsqrtf(v3[c] + BN_EPS);
        const float tt = be3[c] - m3[c] * s;
        const float bb = b3[c];
        float mx = 0.0f;                 // relu floor
        #pragma unroll
        for (int mi = 0; mi < 2; ++mi)
            #pragma unroll
            for (int r = 0; r < 4; ++r)
                mx = fmaxf(mx, fmaf(acc1[mi][ni][r] + bb, s, tt));
        mx = fmaxf(mx, __shfl_xor(mx, 16));
        mx = fmaxf(mx, __shfl_xor(mx, 32));
        if (lane < 16)
            atomicMax((int*)&pool[batch * 256 + c], __float_as_int(mx));
    }
}

// ---------------- head Dense(3), wave-parallel ----------------
__global__ __launch_bounds__(256) void head_kernel(const float* __restrict__ pool,
                                                   const float* __restrict__ wd,
                                                   const float* __restrict__ bd,
                                                   float* __restrict__ out) {
    const int b = blockIdx.x;
    const int t = threadIdx.x;
    const int w = t >> 6;
    const int lane = t & 63;
    if (w < 3) {
        float s = 0.f;
        #pragma unroll
        for (int k = 0; k < 256; k += 64)
            s += pool[b * 256 + k + lane] * wd[(k + lane) * 3 + w];
        #pragma unroll
        for (int off = 32; off; off >>= 1) s += __shfl_down(s, off);
        if (lane == 0) out[b * 3 + w] = s + bd[w];
    }
}

extern "C" void kernel_launch(void* const* d_in, const int* in_sizes, int n_in,
                              void* d_out, int out_size, void* d_ws, size_t ws_size,
                              hipStream_t stream) {
    const float* x   = (const float*)d_in[0];
    const float* a   = (const float*)d_in[1];
    const float* eps = (const float*)d_in[2];
    const float* w1  = (const float*)d_in[3];
    const float* b1  = (const float*)d_in[4];
    const float* g1  = (const float*)d_in[5];
    const float* be1 = (const float*)d_in[6];
    const float* m1  = (const float*)d_in[7];
    const float* v1  = (const float*)d_in[8];
    const float* w2  = (const float*)d_in[9];
    const float* b2  = (const float*)d_in[10];
    const float* g2  = (const float*)d_in[11];
    const float* be2 = (const float*)d_in[12];
    const float* m2  = (const float*)d_in[13];
    const float* v2  = (const float*)d_in[14];
    const float* w3  = (const float*)d_in[15];
    const float* b3  = (const float*)d_in[16];
    const float* g3  = (const float*)d_in[17];
    const float* be3 = (const float*)d_in[18];
    const float* m3  = (const float*)d_in[19];
    const float* v3  = (const float*)d_in[20];
    const float* wd  = (const float*)d_in[21];
    const float* bd  = (const float*)d_in[22];
    float* out = (float*)d_out;

    // Workspace: Xp @0 (16MB), Wp @16M (640KB), abits @17M (4MB), pool @21M (32KB)
    char* ws = (char*)d_ws;
    ushort* Xp    = (ushort*)(ws);
    ushort* Wp    = (ushort*)(ws + (16u << 20));
    uint*   abits = (uint*)  (ws + (17u << 20));
    float*  pool  = (float*) (ws + (21u << 20));

    prep_a<<<4096, 256, 0, stream>>>(a, abits);
    prep_w<<<640, 256, 0, stream>>>(w1, w2, w3, Wp, pool);
    prep_x<<<1024, 512, 0, stream>>>(x, Xp);
    mega_gin<<<512, 512, 0, stream>>>(x, abits, Xp, Wp, eps,
        b1, g1, be1, m1, v1,
        b2, g2, be2, m2, v2,
        b3, g3, be3, m3, v3, pool);
    head_kernel<<<32, 256, 0, stream>>>(pool, wd, bd, out);
}